// Round 7
// baseline (534.025 us; speedup 1.0000x reference)
//
#include <hip/hip_runtime.h>
#include <math.h>

#define NN 4096
#define FF 32
#define DD 16
#define EE 65536

__device__ __forceinline__ int l_of(int i){ return (i==0)?0:(i<4)?1:(i<9)?2:3; }
__device__ __forceinline__ float silu(float v){ return v/(1.f+expf(-v)); }

// ---------- x = per_l_linear(node_feats, W_up) ----------
__global__ __launch_bounds__(512) void k_x(const float* __restrict__ feats,
        const float* __restrict__ Wup, float* __restrict__ x){
  __shared__ float sF[FF*DD];
  __shared__ float sW[4*FF*FF];
  int n = blockIdx.x, t = threadIdx.x;
  sF[t] = feats[(size_t)n*FF*DD + t];
  for (int k=t;k<4*FF*FF;k+=512) sW[k]=Wup[k];
  __syncthreads();
  int f = t>>4, i = t&15;
  const float* W = &sW[l_of(i)*FF*FF];
  float a=0.f;
  #pragma unroll
  for (int c=0;c<FF;c++) a += sF[c*DD+i]*W[c*FF+f];
  x[(size_t)n*FF*DD + t] = a;
}

// ---------- spherical harmonics -> sorted slots ----------
__global__ __launch_bounds__(256) void k_Y(const float* __restrict__ vec,
        const int* __restrict__ epos, float* __restrict__ Yp){
  int e = blockIdx.x*256+threadIdx.x;
  if (e>=EE) return;
  float vx=vec[(size_t)e*3+0], vy=vec[(size_t)e*3+1], vz=vec[(size_t)e*3+2];
  float r2=vx*vx+vy*vy+vz*vz;
  float inv = (r2==0.f)?1.f:rsqrtf(r2);
  float X=vx*inv, Y=vy*inv, Z=vz*inv;
  const float s3=1.7320508075688772f, s5=2.23606797749979f, s7=2.6457513110645907f;
  const float s15=3.872983346207417f, s42=6.48074069840786f, s70=8.366600265340756f, s105=10.246950765959598f;
  float y[16];
  y[0]=s3*X; y[1]=s3*Y; y[2]=s3*Z;
  y[3]=s15*X*Y; y[4]=s15*Y*Z; y[5]=0.5f*s5*(3.f*Z*Z-1.f); y[6]=s15*X*Z; y[7]=0.5f*s15*(X*X-Y*Y);
  y[8]=0.25f*s70*Y*(3.f*X*X-Y*Y); y[9]=s105*X*Y*Z; y[10]=0.25f*s42*Y*(5.f*Z*Z-1.f);
  y[11]=0.5f*s7*Z*(5.f*Z*Z-3.f); y[12]=0.25f*s42*X*(5.f*Z*Z-1.f);
  y[13]=0.5f*s105*Z*(X*X-Y*Y); y[14]=0.25f*s70*X*(X*X-3.f*Y*Y);
  y[15]=0.f;
  size_t ep = (size_t)epos[e];
  #pragma unroll
  for(int q=0;q<4;q++) *(float4*)&Yp[ep*16+q*4] = *(float4*)&y[q*4];
}

// ---------- radial MLP -> mix_s (sorted slots) ----------
__global__ __launch_bounds__(256) void k_mix(const float* __restrict__ rad,
    const float* __restrict__ W1, const float* __restrict__ W2,
    const float* __restrict__ W3, const float* __restrict__ W4,
    const int* __restrict__ epos, float* __restrict__ mix){
  __shared__ float sRadT[8*68];
  __shared__ float sW1[8*64];
  __shared__ float sHA[64*68];
  __shared__ float sHB[64*68];
  int t = threadIdx.x;
  int be = blockIdx.x*64;
  for (int k=t;k<8*64;k+=256) sW1[k]=W1[k];
  for (int idx=t; idx<64*8; idx+=256){ int e=idx>>3, k=idx&7; sRadT[k*68+e]=rad[(size_t)(be+e)*8+k]; }
  __syncthreads();
  int e0 = (t>>4)*4, j0 = (t&15)*4;
  {
    float acc[4][4];
    #pragma unroll
    for(int a=0;a<4;a++){ acc[a][0]=0;acc[a][1]=0;acc[a][2]=0;acc[a][3]=0; }
    #pragma unroll
    for(int k=0;k<8;k++){
      float4 h = *(const float4*)&sRadT[k*68+e0];
      float4 w = *(const float4*)&sW1[k*64+j0];
      acc[0][0]+=h.x*w.x; acc[0][1]+=h.x*w.y; acc[0][2]+=h.x*w.z; acc[0][3]+=h.x*w.w;
      acc[1][0]+=h.y*w.x; acc[1][1]+=h.y*w.y; acc[1][2]+=h.y*w.z; acc[1][3]+=h.y*w.w;
      acc[2][0]+=h.z*w.x; acc[2][1]+=h.z*w.y; acc[2][2]+=h.z*w.z; acc[2][3]+=h.z*w.w;
      acc[3][0]+=h.w*w.x; acc[3][1]+=h.w*w.y; acc[3][2]+=h.w*w.z; acc[3][3]+=h.w*w.w;
    }
    #pragma unroll
    for(int b=0;b<4;b++){
      float4 v; v.x=silu(acc[0][b]); v.y=silu(acc[1][b]); v.z=silu(acc[2][b]); v.w=silu(acc[3][b]);
      *(float4*)&sHA[(j0+b)*68+e0] = v;
    }
  }
  __syncthreads();
  {
    float acc[4][4];
    #pragma unroll
    for(int a=0;a<4;a++){ acc[a][0]=0;acc[a][1]=0;acc[a][2]=0;acc[a][3]=0; }
    for(int k=0;k<64;k++){
      float4 h = *(const float4*)&sHA[k*68+e0];
      float4 w = *(const float4*)&W2[k*64+j0];
      acc[0][0]+=h.x*w.x; acc[0][1]+=h.x*w.y; acc[0][2]+=h.x*w.z; acc[0][3]+=h.x*w.w;
      acc[1][0]+=h.y*w.x; acc[1][1]+=h.y*w.y; acc[1][2]+=h.y*w.z; acc[1][3]+=h.y*w.w;
      acc[2][0]+=h.z*w.x; acc[2][1]+=h.z*w.y; acc[2][2]+=h.z*w.z; acc[2][3]+=h.z*w.w;
      acc[3][0]+=h.w*w.x; acc[3][1]+=h.w*w.y; acc[3][2]+=h.w*w.z; acc[3][3]+=h.w*w.w;
    }
    #pragma unroll
    for(int b=0;b<4;b++){
      float4 v; v.x=silu(acc[0][b]); v.y=silu(acc[1][b]); v.z=silu(acc[2][b]); v.w=silu(acc[3][b]);
      *(float4*)&sHB[(j0+b)*68+e0] = v;
    }
  }
  __syncthreads();
  {
    float acc[4][4];
    #pragma unroll
    for(int a=0;a<4;a++){ acc[a][0]=0;acc[a][1]=0;acc[a][2]=0;acc[a][3]=0; }
    for(int k=0;k<64;k++){
      float4 h = *(const float4*)&sHB[k*68+e0];
      float4 w = *(const float4*)&W3[k*64+j0];
      acc[0][0]+=h.x*w.x; acc[0][1]+=h.x*w.y; acc[0][2]+=h.x*w.z; acc[0][3]+=h.x*w.w;
      acc[1][0]+=h.y*w.x; acc[1][1]+=h.y*w.y; acc[1][2]+=h.y*w.z; acc[1][3]+=h.y*w.w;
      acc[2][0]+=h.z*w.x; acc[2][1]+=h.z*w.y; acc[2][2]+=h.z*w.z; acc[2][3]+=h.z*w.w;
      acc[3][0]+=h.w*w.x; acc[3][1]+=h.w*w.y; acc[3][2]+=h.w*w.z; acc[3][3]+=h.w*w.w;
    }
    #pragma unroll
    for(int b=0;b<4;b++){
      float4 v; v.x=silu(acc[0][b]); v.y=silu(acc[1][b]); v.z=silu(acc[2][b]); v.w=silu(acc[3][b]);
      *(float4*)&sHA[(j0+b)*68+e0] = v;
    }
  }
  __syncthreads();
  {
    int cc0 = (t&63)*4, g = t>>6;
    float acc[4][4][4];
    #pragma unroll
    for(int r=0;r<4;r++)
      #pragma unroll
      for(int a=0;a<4;a++){ acc[r][a][0]=0;acc[r][a][1]=0;acc[r][a][2]=0;acc[r][a][3]=0; }
    for(int k=0;k<64;k++){
      float4 w = *(const float4*)&W4[k*256+cc0];
      #pragma unroll
      for(int r=0;r<4;r++){
        float4 h = *(const float4*)&sHA[k*68 + (g+4*r)*4];
        acc[r][0][0]+=h.x*w.x; acc[r][0][1]+=h.x*w.y; acc[r][0][2]+=h.x*w.z; acc[r][0][3]+=h.x*w.w;
        acc[r][1][0]+=h.y*w.x; acc[r][1][1]+=h.y*w.y; acc[r][1][2]+=h.y*w.z; acc[r][1][3]+=h.y*w.w;
        acc[r][2][0]+=h.z*w.x; acc[r][2][1]+=h.z*w.y; acc[r][2][2]+=h.z*w.z; acc[r][2][3]+=h.z*w.w;
        acc[r][3][0]+=h.w*w.x; acc[r][3][1]+=h.w*w.y; acc[r][3][2]+=h.w*w.z; acc[r][3][3]+=h.w*w.w;
      }
    }
    #pragma unroll
    for(int r=0;r<4;r++)
      #pragma unroll
      for(int a=0;a<4;a++){
        int e = (g+4*r)*4 + a;
        size_t ep = (size_t)epos[be+e];
        float4 v; v.x=acc[r][a][0]; v.y=acc[r][a][1]; v.z=acc[r][a][2]; v.w=acc[r][a][3];
        *(float4*)&mix[ep*256 + cc0] = v;
      }
  }
}

// ---------- CSR build ----------
__global__ void k_zero(int* cnt){ int t=blockIdx.x*256+threadIdx.x; if(t<NN) cnt[t]=0; }
__global__ void k_count(const int* __restrict__ recv, int* cnt, int* pos){
  int e=blockIdx.x*256+threadIdx.x; pos[e]=atomicAdd(&cnt[recv[e]],1); }
__global__ __launch_bounds__(256) void k_scan(const int* __restrict__ cnt, int* __restrict__ off){
  __shared__ int sums[256]; __shared__ int bases[256];
  int t=threadIdx.x;
  int local[16]; int s=0;
  #pragma unroll
  for(int k=0;k<16;k++){ local[k]=cnt[t*16+k]; s+=local[k]; }
  sums[t]=s; __syncthreads();
  if(t==0){ int a=0; for(int q=0;q<256;q++){ bases[q]=a; a+=sums[q]; } }
  __syncthreads();
  int acc=bases[t];
  #pragma unroll
  for(int k=0;k<16;k++){ off[t*16+k]=acc; acc+=local[k]; }
  if(t==255) off[NN]=acc;
}
__global__ void k_fill(const int* __restrict__ recv, const int* __restrict__ off,
                       const int* __restrict__ pos, int* __restrict__ elist){
  int e=blockIdx.x*256+threadIdx.x; elist[off[recv[e]]+pos[e]]=e; }

// ---------- per-node rank sort -> epos (edge->slot), ssend (slot->sender) ----------
__global__ __launch_bounds__(256) void k_sort(const int* __restrict__ senders,
    const int* __restrict__ off, const int* __restrict__ elist,
    int* __restrict__ epos, int* __restrict__ ssend){
  __shared__ int buf[4][256];
  int t=threadIdx.x, w=t>>6, l=t&63;
  int n = blockIdx.x*4 + w;
  int base = off[n];
  int deg = off[n+1]-base; if (deg>256) deg=256;
  for(int d=l; d<deg; d+=64) buf[w][d]=elist[base+d];
  __syncthreads();
  for(int d=l; d<deg; d+=64){
    int v=buf[w][d]; int r=0;
    for(int q=0;q<deg;q++) r += (buf[w][q]<v);
    epos[v] = base + r;
    ssend[base+r] = senders[v];
  }
}

// ---------- compact U3/U2/U1 into per-i sorted lists ----------
__global__ __launch_bounds__(256) void k_compact(const float* __restrict__ U3,
    const float* __restrict__ U2, const float* __restrict__ U1,
    int* u3i, float* u3v, int* u2i, float* u2v, int* u1i, float* u1v, int* uoff){
  const float* src; int n; int* oi; float* ov; int slot=blockIdx.x;
  if(slot==0){src=U3;n=16384;oi=u3i;ov=u3v;}
  else if(slot==1){src=U2;n=1024;oi=u2i;ov=u2v;}
  else {src=U1;n=64;oi=u1i;ov=u1v;}
  __shared__ int cnts[256][4]; __shared__ int bases[256][4];
  int t=threadIdx.x;
  int chunk=(n+255)/256;
  int lo=t*chunk, hi=min(n,lo+chunk); if(lo>n) lo=n;
  int c0=0,c1=0,c2=0,c3=0;
  for(int q=lo;q<hi;q++) if(src[q]!=0.f){
    int i=q&3;
    if(i==0)c0++; else if(i==1)c1++; else if(i==2)c2++; else c3++;
  }
  cnts[t][0]=c0; cnts[t][1]=c1; cnts[t][2]=c2; cnts[t][3]=c3;
  __syncthreads();
  if(t==0){
    int a=0;
    for(int i=0;i<4;i++){ uoff[slot*5+i]=a;
      for(int q=0;q<256;q++){ bases[q][i]=a; a+=cnts[q][i]; } }
    uoff[slot*5+4]=a;
  }
  __syncthreads();
  int w0=bases[t][0], w1_=bases[t][1], w2_=bases[t][2], w3_=bases[t][3];
  for(int q=lo;q<hi;q++){ float v=src[q]; if(v!=0.f){
    int i=q&3;
    if(i==0){ oi[w0]=q; ov[w0]=v; w0++; }
    else if(i==1){ oi[w1_]=q; ov[w1_]=v; w1_++; }
    else if(i==2){ oi[w2_]=q; ov[w2_]=v; w2_++; }
    else { oi[w3_]=q; ov[w3_]=v; w3_++; }
  } }
}

// ---------- fused: edge gather (4 waves/node, prefetch) + Wdown + contraction + out ----------
__global__ __launch_bounds__(256) void k_fused(
    const float* __restrict__ x, const float* __restrict__ mix_s,
    const float* __restrict__ Yp_s, const float* __restrict__ CG,
    const int* __restrict__ off, const int* __restrict__ ssend,
    const float* __restrict__ Wdown,
    const int* __restrict__ u3i, const float* __restrict__ u3v,
    const int* __restrict__ u2i, const float* __restrict__ u2v,
    const int* __restrict__ u1i, const float* __restrict__ u1v,
    const int* __restrict__ uoff,
    const float* __restrict__ w3, const float* __restrict__ w2,
    const float* __restrict__ w1,
    const float* __restrict__ Wsc, const float* __restrict__ Wout,
    const int* __restrict__ species,
    float* __restrict__ out)
{
  __shared__ __align__(16) char smem[23040];
  float* sCG  = (float*)smem;              // [3840] phase1
  float* sMW  = (float*)(smem+15360);      // [4][256] phase1, per-wave private
  int*   sSnd = (int*)(smem+19456);        // [256] phase1
  float* sP   = (float*)smem;              // [4096] phase2 alias (sAgg = sP[0..1024) after reduce)
  float* sy   = (float*)(smem+16384);      // [512]  i*32+c
  float* sXn  = (float*)(smem+18432);      // [512]
  float* sPart= (float*)(smem+20480);      // [512]  w*128 + i*32 + c
  float* sB   = (float*)(smem+22528);      // [128]

  int n = blockIdx.x, t = threadIdx.x;
  int w = t>>6, l = t&63, lc = l&31, kh = (l>>5)*8;
  int li = l>>4, lk = l&15;

  for (int k=t;k<3840;k+=256) sCG[k]=CG[k];
  int base = __builtin_amdgcn_readfirstlane(off[n]);
  int deg  = __builtin_amdgcn_readfirstlane(off[n+1]) - base;
  if (deg>256) deg=256;
  for (int d=t; d<deg; d+=256) sSnd[d]=ssend[base+d];
  __syncthreads();

  float aggF[8], aggT[8];
  #pragma unroll
  for(int j=0;j<8;j++){ aggF[j]=0.f; aggT[j]=0.f; }

  // ---- edge loop: wave w handles d = w, w+4, ...; 1-deep register prefetch ----
  {
    float4 cmF, cmT; float cfs[16], cyv[16];
    if (w < deg){
      int slot = base+w;
      int snd = sSnd[w];
      const float* mrow = mix_s + (size_t)slot*256;
      cmF = *(const float4*)&mrow[lc*4];
      cmT = *(const float4*)&mrow[128 + lc*4];
      const float* xr = x + (size_t)snd*512;
      #pragma unroll
      for(int q=0;q<4;q++) *(float4*)&cfs[q*4] = *(const float4*)&xr[lc*16 + q*4];
      const float* yr = Yp_s + (size_t)slot*16;
      #pragma unroll
      for(int q=0;q<16;q++) cyv[q]=yr[q];
    }
    for (int d=w; d<deg; d+=4){
      int dn = d+4;
      float4 nmF, nmT; float nfs[16], nyv[16];
      if (dn < deg){
        int slot = base+dn;
        int snd = sSnd[dn];
        const float* mrow = mix_s + (size_t)slot*256;
        nmF = *(const float4*)&mrow[lc*4];
        nmT = *(const float4*)&mrow[128 + lc*4];
        const float* xr = x + (size_t)snd*512;
        #pragma unroll
        for(int q=0;q<4;q++) *(float4*)&nfs[q*4] = *(const float4*)&xr[lc*16 + q*4];
        const float* yr = Yp_s + (size_t)slot*16;
        #pragma unroll
        for(int q=0;q<16;q++) nyv[q]=yr[q];
      }
      // compute with current operands
      #pragma unroll
      for(int r=0;r<4;r++){
        int i = r*4+li;
        float m=0.f;
        #pragma unroll
        for(int j=0;j<15;j++) m += cyv[j]*sCG[i*240 + j*16 + lk];
        sMW[w*256 + r*64 + l] = m;
      }
      float tp[8];
      #pragma unroll
      for(int j=0;j<8;j++) tp[j]=0.f;
      #pragma unroll
      for(int i=0;i<16;i++){
        float4 ma = *(const float4*)&sMW[w*256 + i*16 + kh];
        float4 mb = *(const float4*)&sMW[w*256 + i*16 + kh + 4];
        float f = cfs[i];
        tp[0]+=f*ma.x; tp[1]+=f*ma.y; tp[2]+=f*ma.z; tp[3]+=f*ma.w;
        tp[4]+=f*mb.x; tp[5]+=f*mb.y; tp[6]+=f*mb.z; tp[7]+=f*mb.w;
      }
      #pragma unroll
      for(int j=0;j<8;j++){
        int k = kh+j;
        int g = l_of(k);
        float mF = (g==0)?cmF.x:(g==1)?cmF.y:(g==2)?cmF.z:cmF.w;
        float mT = (g==0)?cmT.x:(g==1)?cmT.y:(g==2)?cmT.z:cmT.w;
        aggF[j] += cfs[k]*mF;
        aggT[j] += tp[j]*mT;
      }
      if (dn < deg){
        cmF=nmF; cmT=nmT;
        #pragma unroll
        for(int q=0;q<16;q++){ cfs[q]=nfs[q]; cyv[q]=nyv[q]; }
      }
    }
  }
  __syncthreads();   // all waves done with sCG/sMW before aliasing

  // per-wave partials -> sP, then in-place reduce to sAgg = sP[0..1024)
  #pragma unroll
  for(int j=0;j<8;j++){
    sP[w*1024 + lc*16 + kh + j]       = aggF[j];
    sP[w*1024 + (32+lc)*16 + kh + j]  = aggT[j];
  }
  __syncthreads();
  for (int idx=t; idx<1024; idx+=256)
    sP[idx] = sP[idx]+sP[1024+idx]+sP[2048+idx]+sP[3072+idx];
  __syncthreads();

  // stage skip-connection row; Wdown on first 128 threads
  sXn[t]     = x[(size_t)n*512 + t];
  sXn[256+t] = x[(size_t)n*512 + 256 + t];
  if (t<128){
    int ii=t>>3, f0=(t&7)*4;
    const float* W = Wdown + l_of(ii)*2048;
    float ax=0.f, ay=0.f, az=0.f, aw=0.f;
    for(int c=0;c<64;c++){
      float a = sP[c*16 + ii];
      float4 wv = *(const float4*)&W[c*32+f0];
      ax+=a*wv.x; ay+=a*wv.y; az+=a*wv.z; aw+=a*wv.w;
    }
    sy[ii*32 + f0+0]=ax*0.0625f;
    sy[ii*32 + f0+1]=ay*0.0625f;
    sy[ii*32 + f0+2]=az*0.0625f;
    sy[ii*32 + f0+3]=aw*0.0625f;
  }
  __syncthreads();

  // sparse contraction: stream = wave (uniform scalar term loads); halves duplicate
  int spec = __builtin_amdgcn_readfirstlane(species[n]);
  {
    int c = t&31;
    const float* syc = &sy[c];
    float w3a=w3[spec*64+c], w3b=w3[spec*64+32+c];
    float w2a=w2[spec*64+c], w2b=w2[spec*64+32+c];
    float w1a=w1[spec*64+c], w1b=w1[spec*64+32+c];
    #pragma unroll
    for(int i=0;i<4;i++){
      float r3=0.f;
      for(int q=uoff[i]+w; q<uoff[i+1]; q+=4){
        int id=u3i[q]; float v=u3v[q];
        int a=(id>>10)&15, b=(id>>6)&15, j=(id>>2)&15;
        r3 += v*syc[a*32]*syc[b*32]*syc[j*32];
      }
      float r2=0.f;
      for(int q=uoff[5+i]+w; q<uoff[5+i+1]; q+=4){
        int id=u2i[q]; float v=u2v[q];
        int a=(id>>6)&15, b=(id>>2)&15;
        r2 += v*syc[a*32]*syc[b*32];
      }
      float r1=0.f;
      for(int q=uoff[10+i]+w; q<uoff[10+i+1]; q+=4){
        int id=u1i[q]; float v=u1v[q];
        int a=(id>>2)&15;
        r1 += v*syc[a*32];
      }
      float wa = (i==0)? w3a : w3b;
      float wb = (i==0)? w2a : w2b;
      float wc = (i==0)? w1a : w1b;
      sPart[w*128 + i*32 + c] = r3*wa + r2*wb + r1*wc;
    }
  }
  __syncthreads();
  if (t<128){
    int i2=t>>5, c2=t&31;
    int o = i2*32 + c2;
    sB[c2*4 + i2] = sPart[o] + sPart[128+o] + sPart[256+o] + sPart[384+o];
  }
  __syncthreads();
  if (t<128){
    int f=t>>2, i3=t&3;
    int sel = (i3==0)?0:1;
    const float* Wo = Wout + sel*1024;
    const float* Ws = Wsc + (size_t)(sel*64+spec)*1024;
    float o=0.f, sc=0.f;
    for(int c2=0;c2<32;c2++){
      o  += sB[c2*4 + i3]*Wo[c2*32+f];
      sc += sXn[c2*16 + i3]*Ws[c2*32+f];
    }
    out[(size_t)n*128 + f*4 + i3] = o + sc;
  }
}

extern "C" void kernel_launch(void* const* d_in, const int* in_sizes, int n_in,
                              void* d_out, int out_size, void* d_ws, size_t ws_size,
                              hipStream_t stream){
  (void)in_sizes; (void)n_in; (void)out_size; (void)ws_size;
  const float* feats = (const float*)d_in[0];
  const float* vec   = (const float*)d_in[1];
  const float* rad   = (const float*)d_in[2];
  const float* Wup   = (const float*)d_in[3];
  const float* CG    = (const float*)d_in[4];
  const float* Wr1   = (const float*)d_in[5];
  const float* Wr2   = (const float*)d_in[6];
  const float* Wr3   = (const float*)d_in[7];
  const float* Wr4   = (const float*)d_in[8];
  const float* Wdown = (const float*)d_in[9];
  const float* U3    = (const float*)d_in[10];
  const float* U2    = (const float*)d_in[11];
  const float* U1    = (const float*)d_in[12];
  const float* w3    = (const float*)d_in[13];
  const float* w2    = (const float*)d_in[14];
  const float* w1    = (const float*)d_in[15];
  const float* Wsc   = (const float*)d_in[16];
  const float* Wout  = (const float*)d_in[17];
  const int* species = (const int*)d_in[18];
  const int* senders = (const int*)d_in[19];
  const int* recv    = (const int*)d_in[20];
  float* out = (float*)d_out;

  char* w = (char*)d_ws;
  float* x    = (float*)w;  w += (size_t)NN*512*4;
  float* mix  = (float*)w;  w += (size_t)EE*256*4;
  float* Yp   = (float*)w;  w += (size_t)EE*16*4;
  int* cnt    = (int*)w;    w += (size_t)NN*4;
  int* off    = (int*)w;    w += (size_t)(NN+1)*4;
  int* pos    = (int*)w;    w += (size_t)EE*4;
  int* elist  = (int*)w;    w += (size_t)EE*4;
  int* epos   = (int*)w;    w += (size_t)EE*4;
  int* ssend  = (int*)w;    w += (size_t)EE*4;
  int* u3i    = (int*)w;    w += 16384*4;
  float* u3v  = (float*)w;  w += 16384*4;
  int* u2i    = (int*)w;    w += 1024*4;
  float* u2v  = (float*)w;  w += 1024*4;
  int* u1i    = (int*)w;    w += 64*4;
  float* u1v  = (float*)w;  w += 64*4;
  int* uoff   = (int*)w;    w += 16*4;

  k_compact<<<3,256,0,stream>>>(U3,U2,U1,u3i,u3v,u2i,u2v,u1i,u1v,uoff);
  k_x<<<NN,512,0,stream>>>(feats,Wup,x);
  k_zero<<<NN/256,256,0,stream>>>(cnt);
  k_count<<<EE/256,256,0,stream>>>(recv,cnt,pos);
  k_scan<<<1,256,0,stream>>>(cnt,off);
  k_fill<<<EE/256,256,0,stream>>>(recv,off,pos,elist);
  k_sort<<<NN/4,256,0,stream>>>(senders,off,elist,epos,ssend);
  k_Y<<<EE/256,256,0,stream>>>(vec,epos,Yp);
  k_mix<<<EE/64,256,0,stream>>>(rad,Wr1,Wr2,Wr3,Wr4,epos,mix);
  k_fused<<<NN,256,0,stream>>>(x,mix,Yp,CG,off,ssend,Wdown,
                               u3i,u3v,u2i,u2v,u1i,u1v,uoff,
                               w3,w2,w1,Wsc,Wout,species,out);
}

// Round 8
// 328.539 us; speedup vs baseline: 1.6255x; 1.6255x over previous
//
#include <hip/hip_runtime.h>
#include <math.h>

#define NN 4096
#define FF 32
#define DD 16
#define EE 65536

__device__ __forceinline__ int l_of(int i){ return (i==0)?0:(i<4)?1:(i<9)?2:3; }
__device__ __forceinline__ float silu(float v){ return v/(1.f+expf(-v)); }

// ---------- x = per_l_linear(node_feats, W_up) ----------
__global__ __launch_bounds__(512) void k_x(const float* __restrict__ feats,
        const float* __restrict__ Wup, float* __restrict__ x){
  __shared__ float sF[FF*DD];
  __shared__ float sW[4*FF*FF];
  int n = blockIdx.x, t = threadIdx.x;
  sF[t] = feats[(size_t)n*FF*DD + t];
  for (int k=t;k<4*FF*FF;k+=512) sW[k]=Wup[k];
  __syncthreads();
  int f = t>>4, i = t&15;
  const float* W = &sW[l_of(i)*FF*FF];
  float a=0.f;
  #pragma unroll
  for (int c=0;c<FF;c++) a += sF[c*DD+i]*W[c*FF+f];
  x[(size_t)n*FF*DD + t] = a;
}

// ---------- spherical harmonics -> sorted slots ----------
__global__ __launch_bounds__(256) void k_Y(const float* __restrict__ vec,
        const int* __restrict__ epos, float* __restrict__ Yp){
  int e = blockIdx.x*256+threadIdx.x;
  if (e>=EE) return;
  float vx=vec[(size_t)e*3+0], vy=vec[(size_t)e*3+1], vz=vec[(size_t)e*3+2];
  float r2=vx*vx+vy*vy+vz*vz;
  float inv = (r2==0.f)?1.f:rsqrtf(r2);
  float X=vx*inv, Y=vy*inv, Z=vz*inv;
  const float s3=1.7320508075688772f, s5=2.23606797749979f, s7=2.6457513110645907f;
  const float s15=3.872983346207417f, s42=6.48074069840786f, s70=8.366600265340756f, s105=10.246950765959598f;
  float y[16];
  y[0]=s3*X; y[1]=s3*Y; y[2]=s3*Z;
  y[3]=s15*X*Y; y[4]=s15*Y*Z; y[5]=0.5f*s5*(3.f*Z*Z-1.f); y[6]=s15*X*Z; y[7]=0.5f*s15*(X*X-Y*Y);
  y[8]=0.25f*s70*Y*(3.f*X*X-Y*Y); y[9]=s105*X*Y*Z; y[10]=0.25f*s42*Y*(5.f*Z*Z-1.f);
  y[11]=0.5f*s7*Z*(5.f*Z*Z-3.f); y[12]=0.25f*s42*X*(5.f*Z*Z-1.f);
  y[13]=0.5f*s105*Z*(X*X-Y*Y); y[14]=0.25f*s70*X*(X*X-3.f*Y*Y);
  y[15]=0.f;
  size_t ep = (size_t)epos[e];
  #pragma unroll
  for(int q=0;q<4;q++) *(float4*)&Yp[ep*16+q*4] = *(float4*)&y[q*4];
}

// ---------- radial MLP -> mix_s (sorted slots) ----------
__global__ __launch_bounds__(256) void k_mix(const float* __restrict__ rad,
    const float* __restrict__ W1, const float* __restrict__ W2,
    const float* __restrict__ W3, const float* __restrict__ W4,
    const int* __restrict__ epos, float* __restrict__ mix){
  __shared__ float sRadT[8*68];
  __shared__ float sW1[8*64];
  __shared__ float sHA[64*68];
  __shared__ float sHB[64*68];
  int t = threadIdx.x;
  int be = blockIdx.x*64;
  for (int k=t;k<8*64;k+=256) sW1[k]=W1[k];
  for (int idx=t; idx<64*8; idx+=256){ int e=idx>>3, k=idx&7; sRadT[k*68+e]=rad[(size_t)(be+e)*8+k]; }
  __syncthreads();
  int e0 = (t>>4)*4, j0 = (t&15)*4;
  {
    float acc[4][4];
    #pragma unroll
    for(int a=0;a<4;a++){ acc[a][0]=0;acc[a][1]=0;acc[a][2]=0;acc[a][3]=0; }
    #pragma unroll
    for(int k=0;k<8;k++){
      float4 h = *(const float4*)&sRadT[k*68+e0];
      float4 w = *(const float4*)&sW1[k*64+j0];
      acc[0][0]+=h.x*w.x; acc[0][1]+=h.x*w.y; acc[0][2]+=h.x*w.z; acc[0][3]+=h.x*w.w;
      acc[1][0]+=h.y*w.x; acc[1][1]+=h.y*w.y; acc[1][2]+=h.y*w.z; acc[1][3]+=h.y*w.w;
      acc[2][0]+=h.z*w.x; acc[2][1]+=h.z*w.y; acc[2][2]+=h.z*w.z; acc[2][3]+=h.z*w.w;
      acc[3][0]+=h.w*w.x; acc[3][1]+=h.w*w.y; acc[3][2]+=h.w*w.z; acc[3][3]+=h.w*w.w;
    }
    #pragma unroll
    for(int b=0;b<4;b++){
      float4 v; v.x=silu(acc[0][b]); v.y=silu(acc[1][b]); v.z=silu(acc[2][b]); v.w=silu(acc[3][b]);
      *(float4*)&sHA[(j0+b)*68+e0] = v;
    }
  }
  __syncthreads();
  {
    float acc[4][4];
    #pragma unroll
    for(int a=0;a<4;a++){ acc[a][0]=0;acc[a][1]=0;acc[a][2]=0;acc[a][3]=0; }
    for(int k=0;k<64;k++){
      float4 h = *(const float4*)&sHA[k*68+e0];
      float4 w = *(const float4*)&W2[k*64+j0];
      acc[0][0]+=h.x*w.x; acc[0][1]+=h.x*w.y; acc[0][2]+=h.x*w.z; acc[0][3]+=h.x*w.w;
      acc[1][0]+=h.y*w.x; acc[1][1]+=h.y*w.y; acc[1][2]+=h.y*w.z; acc[1][3]+=h.y*w.w;
      acc[2][0]+=h.z*w.x; acc[2][1]+=h.z*w.y; acc[2][2]+=h.z*w.z; acc[2][3]+=h.z*w.w;
      acc[3][0]+=h.w*w.x; acc[3][1]+=h.w*w.y; acc[3][2]+=h.w*w.z; acc[3][3]+=h.w*w.w;
    }
    #pragma unroll
    for(int b=0;b<4;b++){
      float4 v; v.x=silu(acc[0][b]); v.y=silu(acc[1][b]); v.z=silu(acc[2][b]); v.w=silu(acc[3][b]);
      *(float4*)&sHB[(j0+b)*68+e0] = v;
    }
  }
  __syncthreads();
  {
    float acc[4][4];
    #pragma unroll
    for(int a=0;a<4;a++){ acc[a][0]=0;acc[a][1]=0;acc[a][2]=0;acc[a][3]=0; }
    for(int k=0;k<64;k++){
      float4 h = *(const float4*)&sHB[k*68+e0];
      float4 w = *(const float4*)&W3[k*64+j0];
      acc[0][0]+=h.x*w.x; acc[0][1]+=h.x*w.y; acc[0][2]+=h.x*w.z; acc[0][3]+=h.x*w.w;
      acc[1][0]+=h.y*w.x; acc[1][1]+=h.y*w.y; acc[1][2]+=h.y*w.z; acc[1][3]+=h.y*w.w;
      acc[2][0]+=h.z*w.x; acc[2][1]+=h.z*w.y; acc[2][2]+=h.z*w.z; acc[2][3]+=h.z*w.w;
      acc[3][0]+=h.w*w.x; acc[3][1]+=h.w*w.y; acc[3][2]+=h.w*w.z; acc[3][3]+=h.w*w.w;
    }
    #pragma unroll
    for(int b=0;b<4;b++){
      float4 v; v.x=silu(acc[0][b]); v.y=silu(acc[1][b]); v.z=silu(acc[2][b]); v.w=silu(acc[3][b]);
      *(float4*)&sHA[(j0+b)*68+e0] = v;
    }
  }
  __syncthreads();
  {
    int cc0 = (t&63)*4, g = t>>6;
    float acc[4][4][4];
    #pragma unroll
    for(int r=0;r<4;r++)
      #pragma unroll
      for(int a=0;a<4;a++){ acc[r][a][0]=0;acc[r][a][1]=0;acc[r][a][2]=0;acc[r][a][3]=0; }
    for(int k=0;k<64;k++){
      float4 w = *(const float4*)&W4[k*256+cc0];
      #pragma unroll
      for(int r=0;r<4;r++){
        float4 h = *(const float4*)&sHA[k*68 + (g+4*r)*4];
        acc[r][0][0]+=h.x*w.x; acc[r][0][1]+=h.x*w.y; acc[r][0][2]+=h.x*w.z; acc[r][0][3]+=h.x*w.w;
        acc[r][1][0]+=h.y*w.x; acc[r][1][1]+=h.y*w.y; acc[r][1][2]+=h.y*w.z; acc[r][1][3]+=h.y*w.w;
        acc[r][2][0]+=h.z*w.x; acc[r][2][1]+=h.z*w.y; acc[r][2][2]+=h.z*w.z; acc[r][2][3]+=h.z*w.w;
        acc[r][3][0]+=h.w*w.x; acc[r][3][1]+=h.w*w.y; acc[r][3][2]+=h.w*w.z; acc[r][3][3]+=h.w*w.w;
      }
    }
    #pragma unroll
    for(int r=0;r<4;r++)
      #pragma unroll
      for(int a=0;a<4;a++){
        int e = (g+4*r)*4 + a;
        size_t ep = (size_t)epos[be+e];
        float4 v; v.x=acc[r][a][0]; v.y=acc[r][a][1]; v.z=acc[r][a][2]; v.w=acc[r][a][3];
        *(float4*)&mix[ep*256 + cc0] = v;
      }
  }
}

// ---------- CSR build ----------
__global__ void k_zero(int* cnt){ int t=blockIdx.x*256+threadIdx.x; if(t<NN) cnt[t]=0; }
__global__ void k_count(const int* __restrict__ recv, int* cnt, int* pos){
  int e=blockIdx.x*256+threadIdx.x; pos[e]=atomicAdd(&cnt[recv[e]],1); }
__global__ __launch_bounds__(256) void k_scan(const int* __restrict__ cnt, int* __restrict__ off){
  __shared__ int sums[256]; __shared__ int bases[256];
  int t=threadIdx.x;
  int local[16]; int s=0;
  #pragma unroll
  for(int k=0;k<16;k++){ local[k]=cnt[t*16+k]; s+=local[k]; }
  sums[t]=s; __syncthreads();
  if(t==0){ int a=0; for(int q=0;q<256;q++){ bases[q]=a; a+=sums[q]; } }
  __syncthreads();
  int acc=bases[t];
  #pragma unroll
  for(int k=0;k<16;k++){ off[t*16+k]=acc; acc+=local[k]; }
  if(t==255) off[NN]=acc;
}
__global__ void k_fill(const int* __restrict__ recv, const int* __restrict__ off,
                       const int* __restrict__ pos, int* __restrict__ elist){
  int e=blockIdx.x*256+threadIdx.x; elist[off[recv[e]]+pos[e]]=e; }

// ---------- per-node rank sort -> epos (edge->slot), ssend (slot->sender) ----------
__global__ __launch_bounds__(256) void k_sort(const int* __restrict__ senders,
    const int* __restrict__ off, const int* __restrict__ elist,
    int* __restrict__ epos, int* __restrict__ ssend){
  __shared__ int buf[4][256];
  int t=threadIdx.x, w=t>>6, l=t&63;
  int n = blockIdx.x*4 + w;
  int base = off[n];
  int deg = off[n+1]-base; if (deg>256) deg=256;
  for(int d=l; d<deg; d+=64) buf[w][d]=elist[base+d];
  __syncthreads();
  for(int d=l; d<deg; d+=64){
    int v=buf[w][d]; int r=0;
    for(int q=0;q<deg;q++) r += (buf[w][q]<v);
    epos[v] = base + r;
    ssend[base+r] = senders[v];
  }
}

// ---------- compact U3/U2/U1 into per-i sorted lists ----------
__global__ __launch_bounds__(256) void k_compact(const float* __restrict__ U3,
    const float* __restrict__ U2, const float* __restrict__ U1,
    int* u3i, float* u3v, int* u2i, float* u2v, int* u1i, float* u1v, int* uoff){
  const float* src; int n; int* oi; float* ov; int slot=blockIdx.x;
  if(slot==0){src=U3;n=16384;oi=u3i;ov=u3v;}
  else if(slot==1){src=U2;n=1024;oi=u2i;ov=u2v;}
  else {src=U1;n=64;oi=u1i;ov=u1v;}
  __shared__ int cnts[256][4]; __shared__ int bases[256][4];
  int t=threadIdx.x;
  int chunk=(n+255)/256;
  int lo=t*chunk, hi=min(n,lo+chunk); if(lo>n) lo=n;
  int c0=0,c1=0,c2=0,c3=0;
  for(int q=lo;q<hi;q++) if(src[q]!=0.f){
    int i=q&3;
    if(i==0)c0++; else if(i==1)c1++; else if(i==2)c2++; else c3++;
  }
  cnts[t][0]=c0; cnts[t][1]=c1; cnts[t][2]=c2; cnts[t][3]=c3;
  __syncthreads();
  if(t==0){
    int a=0;
    for(int i=0;i<4;i++){ uoff[slot*5+i]=a;
      for(int q=0;q<256;q++){ bases[q][i]=a; a+=cnts[q][i]; } }
    uoff[slot*5+4]=a;
  }
  __syncthreads();
  int w0=bases[t][0], w1_=bases[t][1], w2_=bases[t][2], w3_=bases[t][3];
  for(int q=lo;q<hi;q++){ float v=src[q]; if(v!=0.f){
    int i=q&3;
    if(i==0){ oi[w0]=q; ov[w0]=v; w0++; }
    else if(i==1){ oi[w1_]=q; ov[w1_]=v; w1_++; }
    else if(i==2){ oi[w2_]=q; ov[w2_]=v; w2_++; }
    else { oi[w3_]=q; ov[w3_]=v; w3_++; }
  } }
}

// ---------- edge gather: 1 node/block, 4 waves striped, head-of-chain prefetch ----------
__global__ __launch_bounds__(256) void k_gather(
    const float* __restrict__ x, const float* __restrict__ mix_s,
    const float* __restrict__ Yp_s, const float* __restrict__ CG,
    const int* __restrict__ off, const int* __restrict__ ssend,
    float* __restrict__ agg)
{
  __shared__ __align__(16) char smem[20480];
  float* sCG = (float*)smem;            // [3840] phase1
  float* sMW = (float*)(smem+15360);    // [4][256] phase1, per-wave private
  float* sP  = (float*)smem;            // [4096] phase2 alias

  int t=threadIdx.x, w=t>>6, l=t&63, lc=l&31, kh=(l>>5)*8;
  int li=l>>4, lk=l&15;
  for (int k=t;k<3840;k+=256) sCG[k]=CG[k];
  int n = blockIdx.x;
  int base = __builtin_amdgcn_readfirstlane(off[n]);
  int deg  = __builtin_amdgcn_readfirstlane(off[n+1]) - base;
  if (deg>256) deg=256;
  __syncthreads();

  float aggF[8], aggT[8];
  #pragma unroll
  for(int j=0;j<8;j++){ aggF[j]=0.f; aggT[j]=0.f; }

  // prefetch state for first edge of this wave (d = w)
  int pSnd = 0;
  float4 pmF, pmT, py0, py1, py2, py3;
  if (w < deg){
    int slot = base + w;
    pSnd = __builtin_amdgcn_readfirstlane(ssend[slot]);
    const float* mrow = mix_s + (size_t)slot*256;
    pmF = *(const float4*)&mrow[lc*4];
    pmT = *(const float4*)&mrow[128 + lc*4];
    const float* yr = Yp_s + (size_t)slot*16;
    py0 = *(const float4*)&yr[0];  py1 = *(const float4*)&yr[4];
    py2 = *(const float4*)&yr[8];  py3 = *(const float4*)&yr[12];
  }

  // no barriers in loop: sMW[w] per-wave private; sCG read-only
  for (int d=w; d<deg; d+=4){
    int snd = pSnd;
    float4 cmF=pmF, cmT=pmT;
    float yv[16];
    *(float4*)&yv[0]=py0; *(float4*)&yv[4]=py1;
    *(float4*)&yv[8]=py2; *(float4*)&yv[12]=py3;
    // issue current x-row load now (snd was prefetched last iter)
    const float* xrow = x + (size_t)snd*512;
    float fsv[16];
    #pragma unroll
    for(int q=0;q<4;q++) *(float4*)&fsv[q*4] = *(const float4*)&xrow[lc*16 + q*4];
    // prefetch next edge's head-of-chain operands
    int dn = d+4;
    if (dn < deg){
      int slot2 = base + dn;
      pSnd = __builtin_amdgcn_readfirstlane(ssend[slot2]);
      const float* mrow2 = mix_s + (size_t)slot2*256;
      pmF = *(const float4*)&mrow2[lc*4];
      pmT = *(const float4*)&mrow2[128 + lc*4];
      const float* yr2 = Yp_s + (size_t)slot2*16;
      py0 = *(const float4*)&yr2[0];  py1 = *(const float4*)&yr2[4];
      py2 = *(const float4*)&yr2[8];  py3 = *(const float4*)&yr2[12];
    }
    // M = Y·CG (yv already resident)
    #pragma unroll
    for(int r=0;r<4;r++){
      int i = r*4+li;
      float m=0.f;
      #pragma unroll
      for(int j=0;j<15;j++) m += yv[j]*sCG[i*240 + j*16 + lk];
      sMW[w*256 + r*64 + l] = m;
    }
    float tp[8];
    #pragma unroll
    for(int j=0;j<8;j++) tp[j]=0.f;
    #pragma unroll
    for(int i=0;i<16;i++){
      float4 ma = *(const float4*)&sMW[w*256 + i*16 + kh];
      float4 mb = *(const float4*)&sMW[w*256 + i*16 + kh + 4];
      float f = fsv[i];
      tp[0]+=f*ma.x; tp[1]+=f*ma.y; tp[2]+=f*ma.z; tp[3]+=f*ma.w;
      tp[4]+=f*mb.x; tp[5]+=f*mb.y; tp[6]+=f*mb.z; tp[7]+=f*mb.w;
    }
    #pragma unroll
    for(int j=0;j<8;j++){
      int k = kh+j;
      int g = l_of(k);
      float mF = (g==0)?cmF.x:(g==1)?cmF.y:(g==2)?cmF.z:cmF.w;
      float mT = (g==0)?cmT.x:(g==1)?cmT.y:(g==2)?cmT.z:cmT.w;
      aggF[j] += fsv[k]*mF;
      aggT[j] += tp[j]*mT;
    }
  }
  __syncthreads();   // all waves done with sCG/sMW before aliasing

  #pragma unroll
  for(int j=0;j<8;j++){
    sP[w*1024 + lc*16 + kh + j]       = aggF[j];
    sP[w*1024 + (32+lc)*16 + kh + j]  = aggT[j];
  }
  __syncthreads();
  for (int idx=t; idx<1024; idx+=256)
    agg[(size_t)n*1024 + idx] = sP[idx]+sP[1024+idx]+sP[2048+idx]+sP[3072+idx];
}

// ---------- tail: Wdown + sparse contraction + output (2 nodes/block) ----------
__global__ __launch_bounds__(256) void k_tail(
    const float* __restrict__ agg, const float* __restrict__ x,
    const float* __restrict__ Wdown,
    const int* __restrict__ u3i, const float* __restrict__ u3v,
    const int* __restrict__ u2i, const float* __restrict__ u2v,
    const int* __restrict__ u1i, const float* __restrict__ u1v,
    const int* __restrict__ uoff,
    const float* __restrict__ w3, const float* __restrict__ w2,
    const float* __restrict__ w1,
    const float* __restrict__ Wsc, const float* __restrict__ Wout,
    const int* __restrict__ species,
    float* __restrict__ out)
{
  __shared__ float sAgg[2048];
  __shared__ float sy[1024];
  __shared__ float sPart[1024];

  int n0 = blockIdx.x*2, t = threadIdx.x;
  #pragma unroll
  for(int q=0;q<8;q++) sAgg[q*256+t] = agg[(size_t)n0*1024 + q*256 + t];
  __syncthreads();

  {
    int h=t>>7, ii=(t>>3)&15, f0=(t&7)*4;
    const float* W = Wdown + l_of(ii)*2048;
    float ax=0.f, ay=0.f, az=0.f, aw=0.f;
    for(int c=0;c<64;c++){
      float a = sAgg[h*1024 + c*16 + ii];
      float4 wv = *(const float4*)&W[c*32+f0];
      ax+=a*wv.x; ay+=a*wv.y; az+=a*wv.z; aw+=a*wv.w;
    }
    sy[h*512 + ii*32 + f0+0]=ax*0.0625f;
    sy[h*512 + ii*32 + f0+1]=ay*0.0625f;
    sy[h*512 + ii*32 + f0+2]=az*0.0625f;
    sy[h*512 + ii*32 + f0+3]=aw*0.0625f;
  }
  __syncthreads();

  float* sXn = sAgg;
  float* sB  = sAgg + 1024;
  #pragma unroll
  for(int q=0;q<4;q++){ int idx=q*256+t;
    sXn[idx] = x[(size_t)(n0+(idx>>9))*512 + (idx&511)]; }

  {
    int p  = __builtin_amdgcn_readfirstlane(t>>6);
    int c  = t&31, hf=(t>>5)&1;
    int spec = species[n0+hf];
    const float* syc = &sy[hf*512 + c];
    #pragma unroll
    for(int i=0;i<4;i++){
      float r3=0.f;
      for(int q=uoff[i]+p; q<uoff[i+1]; q+=4){
        int id=u3i[q]; float v=u3v[q];
        int a=(id>>10)&15, b=(id>>6)&15, j=(id>>2)&15;
        r3 += v*syc[a*32]*syc[b*32]*syc[j*32];
      }
      float r2=0.f;
      for(int q=uoff[5+i]+p; q<uoff[5+i+1]; q+=4){
        int id=u2i[q]; float v=u2v[q];
        int a=(id>>6)&15, b=(id>>2)&15;
        r2 += v*syc[a*32]*syc[b*32];
      }
      float r1=0.f;
      for(int q=uoff[10+i]+p; q<uoff[10+i+1]; q+=4){
        int id=u1i[q]; float v=u1v[q];
        int a=(id>>2)&15;
        r1 += v*syc[a*32];
      }
      float wa = (i==0)? w3[spec*64+c] : w3[spec*64+32+c];
      float wb = (i==0)? w2[spec*64+c] : w2[spec*64+32+c];
      float wc = (i==0)? w1[spec*64+c] : w1[spec*64+32+c];
      sPart[p*256 + i*64 + hf*32 + c] = r3*wa + r2*wb + r1*wc;
    }
  }
  __syncthreads();

  {
    int hf2=t>>7, c2=(t>>2)&31, i2=t&3;
    int o = i2*64 + hf2*32 + c2;
    sB[hf2*128 + c2*4 + i2] = sPart[o] + sPart[256+o] + sPart[512+o] + sPart[768+o];
  }
  __syncthreads();

  {
    int hf3=t>>7, f=(t>>2)&31, i3=t&3;
    int sp2 = species[n0+hf3];
    int sel = (i3==0)?0:1;
    const float* Wo = Wout + sel*1024;
    const float* Ws = Wsc + (size_t)(sel*64+sp2)*1024;
    float o=0.f, sc=0.f;
    for(int c2=0;c2<32;c2++){
      o  += sB[hf3*128 + c2*4 + i3]*Wo[c2*32+f];
      sc += sXn[hf3*512 + c2*16 + i3]*Ws[c2*32+f];
    }
    out[(size_t)(n0+hf3)*128 + f*4 + i3] = o + sc;
  }
}

extern "C" void kernel_launch(void* const* d_in, const int* in_sizes, int n_in,
                              void* d_out, int out_size, void* d_ws, size_t ws_size,
                              hipStream_t stream){
  (void)in_sizes; (void)n_in; (void)out_size; (void)ws_size;
  const float* feats = (const float*)d_in[0];
  const float* vec   = (const float*)d_in[1];
  const float* rad   = (const float*)d_in[2];
  const float* Wup   = (const float*)d_in[3];
  const float* CG    = (const float*)d_in[4];
  const float* Wr1   = (const float*)d_in[5];
  const float* Wr2   = (const float*)d_in[6];
  const float* Wr3   = (const float*)d_in[7];
  const float* Wr4   = (const float*)d_in[8];
  const float* Wdown = (const float*)d_in[9];
  const float* U3    = (const float*)d_in[10];
  const float* U2    = (const float*)d_in[11];
  const float* U1    = (const float*)d_in[12];
  const float* w3    = (const float*)d_in[13];
  const float* w2    = (const float*)d_in[14];
  const float* w1    = (const float*)d_in[15];
  const float* Wsc   = (const float*)d_in[16];
  const float* Wout  = (const float*)d_in[17];
  const int* species = (const int*)d_in[18];
  const int* senders = (const int*)d_in[19];
  const int* recv    = (const int*)d_in[20];
  float* out = (float*)d_out;

  char* w = (char*)d_ws;
  float* x    = (float*)w;  w += (size_t)NN*512*4;
  float* mix  = (float*)w;  w += (size_t)EE*256*4;
  float* Yp   = (float*)w;  w += (size_t)EE*16*4;
  float* agg  = (float*)w;  w += (size_t)NN*1024*4;
  int* cnt    = (int*)w;    w += (size_t)NN*4;
  int* off    = (int*)w;    w += (size_t)(NN+1)*4;
  int* pos    = (int*)w;    w += (size_t)EE*4;
  int* elist  = (int*)w;    w += (size_t)EE*4;
  int* epos   = (int*)w;    w += (size_t)EE*4;
  int* ssend  = (int*)w;    w += (size_t)EE*4;
  int* u3i    = (int*)w;    w += 16384*4;
  float* u3v  = (float*)w;  w += 16384*4;
  int* u2i    = (int*)w;    w += 1024*4;
  float* u2v  = (float*)w;  w += 1024*4;
  int* u1i    = (int*)w;    w += 64*4;
  float* u1v  = (float*)w;  w += 64*4;
  int* uoff   = (int*)w;    w += 16*4;

  k_compact<<<3,256,0,stream>>>(U3,U2,U1,u3i,u3v,u2i,u2v,u1i,u1v,uoff);
  k_x<<<NN,512,0,stream>>>(feats,Wup,x);
  k_zero<<<NN/256,256,0,stream>>>(cnt);
  k_count<<<EE/256,256,0,stream>>>(recv,cnt,pos);
  k_scan<<<1,256,0,stream>>>(cnt,off);
  k_fill<<<EE/256,256,0,stream>>>(recv,off,pos,elist);
  k_sort<<<NN/4,256,0,stream>>>(senders,off,elist,epos,ssend);
  k_Y<<<EE/256,256,0,stream>>>(vec,epos,Yp);
  k_mix<<<EE/64,256,0,stream>>>(rad,Wr1,Wr2,Wr3,Wr4,epos,mix);
  k_gather<<<NN,256,0,stream>>>(x,mix,Yp,CG,off,ssend,agg);
  k_tail<<<NN/2,256,0,stream>>>(agg,x,Wdown,u3i,u3v,u2i,u2v,u1i,u1v,uoff,
                                w3,w2,w1,Wsc,Wout,species,out);
}